// Round 5
// baseline (419.447 us; speedup 1.0000x reference)
//
#include <hip/hip_runtime.h>

typedef _Float16 half8 __attribute__((ext_vector_type(8)));
typedef _Float16 half4 __attribute__((ext_vector_type(4)));
typedef float    f32x4 __attribute__((ext_vector_type(4)));

#define W_CLS 16
#define SHOT  8
#define C_CH  128
#define HW    1024
#define NSAMP (SHOT*HW)   /* 8192 */
#define B_Q   256

// ================= primary path =================

// ---- cova_part: per (w, k-split) partial gram via fp16 MFMA + mean partials ----
// grid 256 = 16 w x 16 ks (K=512 per block), block 512
__global__ __launch_bounds__(512) void cova_part(const float* __restrict__ x2,
                                                 float* __restrict__ PG,
                                                 float* __restrict__ pmean) {
    __shared__ _Float16 XT[2][128*72];
    __shared__ float mred[128][4];
    int tid = threadIdx.x;
    int w = blockIdx.x >> 4, ks = blockIdx.x & 15;
    int s = ks >> 1, p00 = (ks & 1) * 512;
    int c = tid >> 2, ph = (tid & 3) * 16;
    const float* src = x2 + (((size_t)(w*SHOT + s))*C_CH + c)*HW + p00 + ph;
    int lane = tid & 63, wv = tid >> 6;
    int lr = lane & 15, lg = lane >> 4;
    int mt0 = (wv & 3)*2, nt0 = (wv >> 2)*4;

    float msum = 0.f;
    f32x4 acc[2][4];
    #pragma unroll
    for (int mm = 0; mm < 2; ++mm)
        #pragma unroll
        for (int nn = 0; nn < 4; ++nn) acc[mm][nn] = (f32x4){0.f,0.f,0.f,0.f};

    float4 rg[4];
    #pragma unroll
    for (int j = 0; j < 4; ++j) rg[j] = *(const float4*)(src + j*4);
    #pragma unroll
    for (int j = 0; j < 4; ++j) {
        msum += rg[j].x + rg[j].y + rg[j].z + rg[j].w;
        half4 h = {(_Float16)rg[j].x, (_Float16)rg[j].y, (_Float16)rg[j].z, (_Float16)rg[j].w};
        *(half4*)(&XT[0][c*72 + ph + j*4]) = h;
    }
    __syncthreads();

    for (int ch = 0; ch < 8; ++ch) {
        int buf = ch & 1;
        if (ch < 7) {
            #pragma unroll
            for (int j = 0; j < 4; ++j) rg[j] = *(const float4*)(src + (ch+1)*64 + j*4);
        }
        const _Float16* xb = XT[buf];
        #pragma unroll
        for (int kk = 0; kk < 2; ++kk) {
            half8 Bv[4], Av[2];
            #pragma unroll
            for (int nn = 0; nn < 4; ++nn)
                Bv[nn] = *(const half8*)(xb + ((nt0+nn)*16 + lr)*72 + kk*32 + lg*8);
            #pragma unroll
            for (int mm = 0; mm < 2; ++mm)
                Av[mm] = *(const half8*)(xb + ((mt0+mm)*16 + lr)*72 + kk*32 + lg*8);
            #pragma unroll
            for (int mm = 0; mm < 2; ++mm)
                #pragma unroll
                for (int nn = 0; nn < 4; ++nn)
                    acc[mm][nn] = __builtin_amdgcn_mfma_f32_16x16x32_f16(Av[mm], Bv[nn], acc[mm][nn], 0,0,0);
        }
        if (ch < 7) {
            #pragma unroll
            for (int j = 0; j < 4; ++j) {
                msum += rg[j].x + rg[j].y + rg[j].z + rg[j].w;
                half4 h = {(_Float16)rg[j].x, (_Float16)rg[j].y, (_Float16)rg[j].z, (_Float16)rg[j].w};
                *(half4*)(&XT[buf^1][c*72 + ph + j*4]) = h;
            }
        }
        __syncthreads();
    }

    mred[c][tid & 3] = msum;
    __syncthreads();
    if (tid < 128)
        pmean[((size_t)w*16 + ks)*128 + tid] = mred[tid][0]+mred[tid][1]+mred[tid][2]+mred[tid][3];

    float* pg = PG + ((size_t)w*16 + ks)*16384;
    #pragma unroll
    for (int mm = 0; mm < 2; ++mm)
        #pragma unroll
        for (int nn = 0; nn < 4; ++nn)
            #pragma unroll
            for (int r = 0; r < 4; ++r) {
                int cr = (mt0+mm)*16 + lg*4 + r;
                int d  = (nt0+nn)*16 + lr;
                pg[cr*128 + d] = acc[mm][nn][r];
            }
}

// ---- cova_reduce: sum partials, mean-correct, write U = triu(C, half-diag) ----
__global__ __launch_bounds__(256) void cova_reduce(const float* __restrict__ PG,
                                                   const float* __restrict__ pmean,
                                                   _Float16* __restrict__ Uh) {
    __shared__ float ms[128];
    int t = threadIdx.x;
    int w = blockIdx.x >> 3, rg = blockIdx.x & 7;
    if (t < 128) {
        float sum = 0.f;
        for (int ks = 0; ks < 16; ++ks) sum += pmean[((size_t)w*16 + ks)*128 + t];
        ms[t] = sum * (1.0f/NSAMP);
    }
    __syncthreads();
    const float* pg = PG + (size_t)w*16*16384;
    #pragma unroll
    for (int it = 0; it < 8; ++it) {
        int e = it*256 + t;
        int r = rg*16 + (e >> 7), d = e & 127;
        float g = 0.f;
        for (int ks = 0; ks < 16; ++ks) g += pg[(size_t)ks*16384 + r*128 + d];
        float val = (g - (float)NSAMP*ms[r]*ms[d]) * (1.0f/(NSAMP-1));
        float uval = (d > r) ? val : ((d == r) ? 0.5f*val : 0.0f);
        Uh[((size_t)w*128 + r)*128 + d] = (_Float16)uval;
    }
}

// ---- qconv2: transpose+fp16 cvt of x1 + per-chunk square-sum partials ---------
// grid 1024 = 256 b x 4 i-chunks of 256; block 512
__global__ __launch_bounds__(512) void qconv2_kernel(const float* __restrict__ x1,
                                                     _Float16* __restrict__ qhT,
                                                     float* __restrict__ psq) {
    __shared__ _Float16 T[128*258];
    int tid = threadIdx.x, lane = tid & 63, wv = tid >> 6;
    int b = blockIdx.x >> 2, ic = blockIdx.x & 3, i0 = ic*256;

    // phase 1: wave wv handles c = wv*16..+16; coalesced f32x4 reads, sq-reduce
    #pragma unroll
    for (int cc = 0; cc < 16; ++cc) {
        int c = wv*16 + cc;
        f32x4 v = *(const f32x4*)(x1 + ((size_t)(b*C_CH + c))*HW + i0 + lane*4);
        half4 h = {(_Float16)v[0], (_Float16)v[1], (_Float16)v[2], (_Float16)v[3]};
        *(half4*)(&T[c*258 + lane*4]) = h;
        float sq = v[0]*v[0] + v[1]*v[1] + v[2]*v[2] + v[3]*v[3];
        #pragma unroll
        for (int off = 32; off; off >>= 1) sq += __shfl_xor(sq, off, 64);
        if (lane == 0) psq[((size_t)b*4 + ic)*128 + c] = sq;
    }
    __syncthreads();

    // phase 2: thread t writes row i = t>>1, c-half ch = t&1 (128B per thread)
    int i = tid >> 1, ch = tid & 1;
    _Float16* orow = qhT + ((size_t)(b*HW + i0 + i))*C_CH + ch*64;
    #pragma unroll
    for (int s = 0; s < 8; ++s) {
        half8 pk;
        #pragma unroll
        for (int j = 0; j < 8; ++j) pk[j] = T[(ch*64 + s*8 + j)*258 + i];
        *(half8*)(orow + s*8) = pk;
    }
}

// ---- rfin: rn = 1/sqrt(sum of 4 chunk partials) -------------------------------
__global__ __launch_bounds__(512) void rfin_kernel(const float* __restrict__ psq,
                                                   float* __restrict__ rn) {
    int idx = blockIdx.x*512 + threadIdx.x;   // 0..32767 = b*128+c
    int b = idx >> 7, c = idx & 127;
    float s = psq[((size_t)b*4 + 0)*128 + c] + psq[((size_t)b*4 + 1)*128 + c]
            + psq[((size_t)b*4 + 2)*128 + c] + psq[((size_t)b*4 + 3)*128 + c];
    rn[idx] = 1.0f / sqrtf(s);
}

// ---- sim v5: no LDS, no barriers; q in registers; 16-w loop in-wave -----------
// grid 1024 = 256 b x 4 i-chunks of 256; block 512 = 8 waves x 32 i each
__global__ __launch_bounds__(512, 2) void sim_kernel(const _Float16* __restrict__ qhT,
                                                     const _Float16* __restrict__ Uh,
                                                     const float* __restrict__ rn,
                                                     float* __restrict__ out) {
    int tid = threadIdx.x, lane = tid & 63, wv = tid >> 6;
    int lr = lane & 15, lg = lane >> 4;
    int b = blockIdx.x >> 2, ic = blockIdx.x & 3;
    int ibase = ic*256 + wv*32;

    const _Float16* qb  = qhT + ((size_t)b*HW + ibase)*C_CH;
    const float*    rnb = rn + b*C_CH;

    // B-fragments (normalized in-register): B[kk][nn], lane holds q[i=nn*16+lr][kk*32+lg*8..+8]
    half8 B[4][2];
    #pragma unroll
    for (int kk = 0; kk < 4; ++kk) {
        f32x4 r0 = *(const f32x4*)(rnb + kk*32 + lg*8);
        f32x4 r1 = *(const f32x4*)(rnb + kk*32 + lg*8 + 4);
        half8 rh;
        rh[0]=(_Float16)r0[0]; rh[1]=(_Float16)r0[1]; rh[2]=(_Float16)r0[2]; rh[3]=(_Float16)r0[3];
        rh[4]=(_Float16)r1[0]; rh[5]=(_Float16)r1[1]; rh[6]=(_Float16)r1[2]; rh[7]=(_Float16)r1[3];
        #pragma unroll
        for (int nn = 0; nn < 2; ++nn) {
            half8 v = *(const half8*)(qb + (size_t)(nn*16 + lr)*C_CH + kk*32 + lg*8);
            #pragma unroll
            for (int e = 0; e < 8; ++e) v[e] = v[e] * rh[e];
            B[kk][nn] = v;
        }
    }

    // diag q in acc layout: dq[m][nn] = qn[d = m*16+lg*4 .. +4][i = nn*16+lr]
    half4 dq[8][2];
    #pragma unroll
    for (int m = 0; m < 8; ++m) {
        f32x4 rm = *(const f32x4*)(rnb + m*16 + lg*4);
        half4 rh = {(_Float16)rm[0], (_Float16)rm[1], (_Float16)rm[2], (_Float16)rm[3]};
        #pragma unroll
        for (int nn = 0; nn < 2; ++nn) {
            half4 v = *(const half4*)(qb + (size_t)(nn*16 + lr)*C_CH + m*16 + lg*4);
            #pragma unroll
            for (int r = 0; r < 4; ++r) v[r] = v[r] * rh[r];
            dq[m][nn] = v;
        }
    }

    for (int w = 0; w < W_CLS; ++w) {
        const _Float16* Ub = Uh + (size_t)w*C_CH*C_CH + (size_t)lr*C_CH + lg*8;

        // 20 upper-tri A fragments (m <= 2kk+1), same addrs across waves -> L1-hot
        half8 A[20];
        {
            int idx = 0;
            #pragma unroll
            for (int kk = 0; kk < 4; ++kk)
                #pragma unroll
                for (int m = 0; m <= 2*kk+1; ++m) {
                    A[idx] = *(const half8*)(Ub + (size_t)m*16*C_CH + kk*32);
                    ++idx;
                }
        }

        f32x4 acc[8][2];
        #pragma unroll
        for (int m = 0; m < 8; ++m)
            #pragma unroll
            for (int nn = 0; nn < 2; ++nn) acc[m][nn] = (f32x4){0.f,0.f,0.f,0.f};

        {
            int idx = 0;
            #pragma unroll
            for (int kk = 0; kk < 4; ++kk)
                #pragma unroll
                for (int m = 0; m <= 2*kk+1; ++m) {
                    #pragma unroll
                    for (int nn = 0; nn < 2; ++nn)
                        acc[m][nn] = __builtin_amdgcn_mfma_f32_16x16x32_f16(A[idx], B[kk][nn], acc[m][nn], 0,0,0);
                    ++idx;
                }
        }

        // diag contraction, all in registers
        float s0 = 0.f, s1 = 0.f;
        #pragma unroll
        for (int m = 0; m < 8; ++m) {
            #pragma unroll
            for (int r = 0; r < 4; ++r) {
                s0 = fmaf((float)dq[m][0][r], acc[m][0][r], s0);
                s1 = fmaf((float)dq[m][1][r], acc[m][1][r], s1);
            }
        }
        s0 += __shfl_xor(s0, 16, 64); s0 += __shfl_xor(s0, 32, 64);
        s1 += __shfl_xor(s1, 16, 64); s1 += __shfl_xor(s1, 32, 64);

        if (lane < 32) {
            float v = (lane < 16) ? s0 : s1;
            out[((size_t)b*W_CLS + w)*HW + ibase + (lane & 31)] = 2.0f * v;
        }
    }
}

// ================= fallback path (small ws) =================

__global__ __launch_bounds__(256) void rnorm_kernel(const float* __restrict__ x1,
                                                    float* __restrict__ rn) {
    int row  = blockIdx.x * 4 + (threadIdx.x >> 6);
    int lane = threadIdx.x & 63;
    const float4* p = (const float4*)(x1 + (size_t)row * HW);
    float s = 0.f;
    #pragma unroll
    for (int it = 0; it < 4; ++it) {
        float4 v = p[lane + it * 64];
        s += v.x*v.x + v.y*v.y + v.z*v.z + v.w*v.w;
    }
    for (int off = 32; off; off >>= 1) s += __shfl_down(s, off, 64);
    if (lane == 0) rn[row] = 1.0f / sqrtf(s);
}

__global__ __launch_bounds__(256) void mean_kernel_f(const float* __restrict__ x2,
                                                     float* __restrict__ mean) {
    int wc = blockIdx.x;
    int w  = wc >> 7, c = wc & 127;
    const float* base = x2 + ((size_t)(w * SHOT) * C_CH + c) * HW;
    int tid = threadIdx.x;
    float sum = 0.f;
    for (int s = 0; s < SHOT; ++s) {
        const float* row = base + (size_t)s * C_CH * HW;
        for (int p = tid; p < HW; p += 256) sum += row[p];
    }
    for (int off = 32; off; off >>= 1) sum += __shfl_down(sum, off, 64);
    __shared__ float red[4];
    int lane = tid & 63, wv = tid >> 6;
    if (lane == 0) red[wv] = sum;
    __syncthreads();
    if (tid == 0) mean[wc] = (red[0] + red[1] + red[2] + red[3]) * (1.0f / NSAMP);
}

__global__ __launch_bounds__(256) void cova_kernel_f(const float* __restrict__ x2,
                                                     const float* __restrict__ mean,
                                                     _Float16* __restrict__ covah) {
    int bid = blockIdx.x;
    int w  = bid >> 4;
    int c0 = ((bid >> 2) & 3) * 32;
    int d0 = (bid & 3) * 32;
    __shared__ float As[32][33];
    __shared__ float Bs[32][33];
    int tid = threadIdx.x;
    int ty = tid >> 4, tx = tid & 15;
    int lrr = tid >> 3, lc = (tid & 7) * 4;
    const float* base = x2 + (size_t)w * SHOT * C_CH * HW;
    float acc00 = 0.f, acc01 = 0.f, acc10 = 0.f, acc11 = 0.f;
    for (int k0 = 0; k0 < NSAMP; k0 += 32) {
        int s = k0 >> 10, p = k0 & 1023;
        const float4 a4 = *(const float4*)(base + ((size_t)s * C_CH + (c0 + lrr)) * HW + p + lc);
        const float4 b4 = *(const float4*)(base + ((size_t)s * C_CH + (d0 + lrr)) * HW + p + lc);
        As[lrr][lc+0] = a4.x; As[lrr][lc+1] = a4.y; As[lrr][lc+2] = a4.z; As[lrr][lc+3] = a4.w;
        Bs[lrr][lc+0] = b4.x; Bs[lrr][lc+1] = b4.y; Bs[lrr][lc+2] = b4.z; Bs[lrr][lc+3] = b4.w;
        __syncthreads();
        #pragma unroll
        for (int kk = 0; kk < 32; ++kk) {
            float a0 = As[ty*2][kk],   a1 = As[ty*2+1][kk];
            float b0 = Bs[tx*2][kk],   b1 = Bs[tx*2+1][kk];
            acc00 = fmaf(a0, b0, acc00);
            acc01 = fmaf(a0, b1, acc01);
            acc10 = fmaf(a1, b0, acc10);
            acc11 = fmaf(a1, b1, acc11);
        }
        __syncthreads();
    }
    const float inv = 1.0f / (NSAMP - 1);
    int c = c0 + ty * 2, d = d0 + tx * 2;
    float mc0 = mean[w*128 + c],     mc1 = mean[w*128 + c + 1];
    float md0 = mean[w*128 + d],     md1 = mean[w*128 + d + 1];
    _Float16* o = covah + ((size_t)w * 128 + c) * 128 + d;
    o[0]   = (_Float16)((acc00 - (float)NSAMP * mc0 * md0) * inv);
    o[1]   = (_Float16)((acc01 - (float)NSAMP * mc0 * md1) * inv);
    o[128] = (_Float16)((acc10 - (float)NSAMP * mc1 * md0) * inv);
    o[129] = (_Float16)((acc11 - (float)NSAMP * mc1 * md1) * inv);
}

#define LDQ 136
__global__ __launch_bounds__(512) void sim_kernel_f(const float* __restrict__ x1,
                                                    const _Float16* __restrict__ Ch,
                                                    const float* __restrict__ rn,
                                                    float* __restrict__ out) {
    __shared__ _Float16 qT[128][LDQ];
    __shared__ float simbuf[2][128];
    int tid = threadIdx.x;
    int bq  = blockIdx.x;
    int b   = bq >> 3;
    int i0  = (bq & 7) * 128;
    {
        int c  = tid >> 2;
        int iq = (tid & 3) * 32;
        const float* src = x1 + ((size_t)b * C_CH + c) * HW + i0 + iq;
        float scale = rn[b * C_CH + c];
        #pragma unroll
        for (int j4 = 0; j4 < 8; ++j4) {
            f32x4 v = *(const f32x4*)(src + j4 * 4);
            qT[iq + j4*4 + 0][c] = (_Float16)(v[0] * scale);
            qT[iq + j4*4 + 1][c] = (_Float16)(v[1] * scale);
            qT[iq + j4*4 + 2][c] = (_Float16)(v[2] * scale);
            qT[iq + j4*4 + 3][c] = (_Float16)(v[3] * scale);
        }
    }
    __syncthreads();
    int lane = tid & 63;
    int wv   = tid >> 6;
    int mh   = wv >> 2;
    int nq   = wv & 3;
    int d0w  = mh * 64;
    int iw   = nq * 32;
    int lr   = lane & 15;
    int lg   = lane >> 4;
    float qd[4][2][4];
    #pragma unroll
    for (int m = 0; m < 4; ++m)
        #pragma unroll
        for (int n = 0; n < 2; ++n) {
            half4 hq = *(const half4*)&qT[iw + n*16 + lr][d0w + m*16 + lg*4];
            qd[m][n][0] = (float)hq[0];
            qd[m][n][1] = (float)hq[1];
            qd[m][n][2] = (float)hq[2];
            qd[m][n][3] = (float)hq[3];
        }
    for (int w = 0; w < W_CLS; ++w) {
        const _Float16* Cw = Ch + (size_t)w * C_CH * C_CH;
        half8 A[4][4];
        #pragma unroll
        for (int m = 0; m < 4; ++m)
            #pragma unroll
            for (int k = 0; k < 4; ++k)
                A[m][k] = *(const half8*)(Cw + (size_t)(d0w + m*16 + lr) * C_CH + k*32 + lg*8);
        f32x4 acc[4][2];
        #pragma unroll
        for (int m = 0; m < 4; ++m)
            #pragma unroll
            for (int n = 0; n < 2; ++n)
                acc[m][n] = (f32x4){0.f, 0.f, 0.f, 0.f};
        #pragma unroll
        for (int k = 0; k < 4; ++k) {
            #pragma unroll
            for (int n = 0; n < 2; ++n) {
                half8 Bf = *(const half8*)&qT[iw + n*16 + lr][k*32 + lg*8];
                #pragma unroll
                for (int m = 0; m < 4; ++m)
                    acc[m][n] = __builtin_amdgcn_mfma_f32_16x16x32_f16(A[m][k], Bf, acc[m][n], 0, 0, 0);
            }
        }
        float s0 = 0.f, s1 = 0.f;
        #pragma unroll
        for (int m = 0; m < 4; ++m) {
            #pragma unroll
            for (int r = 0; r < 4; ++r) {
                s0 = fmaf(qd[m][0][r], acc[m][0][r], s0);
                s1 = fmaf(qd[m][1][r], acc[m][1][r], s1);
            }
        }
        s0 += __shfl_xor(s0, 16); s0 += __shfl_xor(s0, 32);
        s1 += __shfl_xor(s1, 16); s1 += __shfl_xor(s1, 32);
        if (lane < 16) {
            simbuf[mh][iw + 0*16 + lane] = s0;
            simbuf[mh][iw + 1*16 + lane] = s1;
        }
        __syncthreads();
        if (tid < 128)
            out[((size_t)b * W_CLS + w) * HW + i0 + tid] = simbuf[0][tid] + simbuf[1][tid];
        __syncthreads();
    }
}

// ================= host =================

extern "C" void kernel_launch(void* const* d_in, const int* in_sizes, int n_in,
                              void* d_out, int out_size, void* d_ws, size_t ws_size,
                              hipStream_t stream) {
    (void)in_sizes; (void)n_in; (void)out_size;
    const float* x1 = (const float*)d_in[0];   // [256,128,32,32]
    const float* x2 = (const float*)d_in[1];   // [16,8,128,32,32]
    float* out = (float*)d_out;

    char* ws = (char*)d_ws;
    const size_t OFF_QHT = 0;                          // 64 MB
    const size_t OFF_PG  = 67108864;                   // 16.78 MB
    const size_t OFF_PM  = OFF_PG  + 16777216;         // 128 KB
    const size_t OFF_UH  = OFF_PM  + 131072;           // 512 KB
    const size_t OFF_RN  = OFF_UH  + 524288;           // 128 KB
    const size_t OFF_PSQ = OFF_RN  + 131072;           // 512 KB
    const size_t NEED    = OFF_PSQ + 524288;

    if (ws_size >= NEED) {
        _Float16* qhT = (_Float16*)(ws + OFF_QHT);
        float*    PG  = (float*)(ws + OFF_PG);
        float*    pm  = (float*)(ws + OFF_PM);
        _Float16* Uh  = (_Float16*)(ws + OFF_UH);
        float*    rn  = (float*)(ws + OFF_RN);
        float*    psq = (float*)(ws + OFF_PSQ);
        cova_part   <<<256,  512, 0, stream>>>(x2, PG, pm);
        cova_reduce <<<128,  256, 0, stream>>>(PG, pm, Uh);
        qconv2_kernel<<<1024, 512, 0, stream>>>(x1, qhT, psq);
        rfin_kernel <<<64,   512, 0, stream>>>(psq, rn);
        sim_kernel  <<<1024, 512, 0, stream>>>(qhT, Uh, rn, out);
    } else {
        float*    mean = (float*)ws;
        float*    rn   = mean + W_CLS*C_CH;
        _Float16* Ch   = (_Float16*)(rn + B_Q*C_CH);
        mean_kernel_f<<<W_CLS*C_CH,  256, 0, stream>>>(x2, mean);
        cova_kernel_f<<<W_CLS*16,    256, 0, stream>>>(x2, mean, Ch);
        rnorm_kernel <<<B_Q*C_CH/4,  256, 0, stream>>>(x1, rn);
        sim_kernel_f <<<B_Q*8,       512, 0, stream>>>(x1, Ch, rn, out);
    }
}

// Round 6
// 216.071 us; speedup vs baseline: 1.9412x; 1.9412x over previous
//
#include <hip/hip_runtime.h>

typedef _Float16 half8 __attribute__((ext_vector_type(8)));
typedef _Float16 half4 __attribute__((ext_vector_type(4)));
typedef float    f32x4 __attribute__((ext_vector_type(4)));

#define W_CLS 16
#define SHOT  8
#define C_CH  128
#define HW    1024
#define NSAMP (SHOT*HW)   /* 8192 */
#define B_Q   256

// ================= primary path =================

// ---- cova_part: per (w, k-split) partial gram via fp16 MFMA + mean partials ----
// grid 256 = 16 w x 16 ks (K=512 per block), block 512
__global__ __launch_bounds__(512) void cova_part(const float* __restrict__ x2,
                                                 float* __restrict__ PG,
                                                 float* __restrict__ pmean) {
    __shared__ _Float16 XT[2][128*72];
    __shared__ float mred[128][4];
    int tid = threadIdx.x;
    int w = blockIdx.x >> 4, ks = blockIdx.x & 15;
    int s = ks >> 1, p00 = (ks & 1) * 512;
    int c = tid >> 2, ph = (tid & 3) * 16;
    const float* src = x2 + (((size_t)(w*SHOT + s))*C_CH + c)*HW + p00 + ph;
    int lane = tid & 63, wv = tid >> 6;
    int lr = lane & 15, lg = lane >> 4;
    int mt0 = (wv & 3)*2, nt0 = (wv >> 2)*4;

    float msum = 0.f;
    f32x4 acc[2][4];
    #pragma unroll
    for (int mm = 0; mm < 2; ++mm)
        #pragma unroll
        for (int nn = 0; nn < 4; ++nn) acc[mm][nn] = (f32x4){0.f,0.f,0.f,0.f};

    float4 rg[4];
    #pragma unroll
    for (int j = 0; j < 4; ++j) rg[j] = *(const float4*)(src + j*4);
    #pragma unroll
    for (int j = 0; j < 4; ++j) {
        msum += rg[j].x + rg[j].y + rg[j].z + rg[j].w;
        half4 h = {(_Float16)rg[j].x, (_Float16)rg[j].y, (_Float16)rg[j].z, (_Float16)rg[j].w};
        *(half4*)(&XT[0][c*72 + ph + j*4]) = h;
    }
    __syncthreads();

    for (int ch = 0; ch < 8; ++ch) {
        int buf = ch & 1;
        if (ch < 7) {
            #pragma unroll
            for (int j = 0; j < 4; ++j) rg[j] = *(const float4*)(src + (ch+1)*64 + j*4);
        }
        const _Float16* xb = XT[buf];
        #pragma unroll
        for (int kk = 0; kk < 2; ++kk) {
            half8 Bv[4], Av[2];
            #pragma unroll
            for (int nn = 0; nn < 4; ++nn)
                Bv[nn] = *(const half8*)(xb + ((nt0+nn)*16 + lr)*72 + kk*32 + lg*8);
            #pragma unroll
            for (int mm = 0; mm < 2; ++mm)
                Av[mm] = *(const half8*)(xb + ((mt0+mm)*16 + lr)*72 + kk*32 + lg*8);
            #pragma unroll
            for (int mm = 0; mm < 2; ++mm)
                #pragma unroll
                for (int nn = 0; nn < 4; ++nn)
                    acc[mm][nn] = __builtin_amdgcn_mfma_f32_16x16x32_f16(Av[mm], Bv[nn], acc[mm][nn], 0,0,0);
        }
        if (ch < 7) {
            #pragma unroll
            for (int j = 0; j < 4; ++j) {
                msum += rg[j].x + rg[j].y + rg[j].z + rg[j].w;
                half4 h = {(_Float16)rg[j].x, (_Float16)rg[j].y, (_Float16)rg[j].z, (_Float16)rg[j].w};
                *(half4*)(&XT[buf^1][c*72 + ph + j*4]) = h;
            }
        }
        __syncthreads();
    }

    mred[c][tid & 3] = msum;
    __syncthreads();
    if (tid < 128)
        pmean[((size_t)w*16 + ks)*128 + tid] = mred[tid][0]+mred[tid][1]+mred[tid][2]+mred[tid][3];

    float* pg = PG + ((size_t)w*16 + ks)*16384;
    #pragma unroll
    for (int mm = 0; mm < 2; ++mm)
        #pragma unroll
        for (int nn = 0; nn < 4; ++nn)
            #pragma unroll
            for (int r = 0; r < 4; ++r) {
                int cr = (mt0+mm)*16 + lg*4 + r;
                int d  = (nt0+nn)*16 + lr;
                pg[cr*128 + d] = acc[mm][nn][r];
            }
}

// ---- cova_reduce: sum partials, mean-correct, write U = triu(C, half-diag) ----
__global__ __launch_bounds__(256) void cova_reduce(const float* __restrict__ PG,
                                                   const float* __restrict__ pmean,
                                                   _Float16* __restrict__ Uh) {
    __shared__ float ms[128];
    int t = threadIdx.x;
    int w = blockIdx.x >> 3, rg = blockIdx.x & 7;
    if (t < 128) {
        float sum = 0.f;
        for (int ks = 0; ks < 16; ++ks) sum += pmean[((size_t)w*16 + ks)*128 + t];
        ms[t] = sum * (1.0f/NSAMP);
    }
    __syncthreads();
    const float* pg = PG + (size_t)w*16*16384;
    #pragma unroll
    for (int it = 0; it < 8; ++it) {
        int e = it*256 + t;
        int r = rg*16 + (e >> 7), d = e & 127;
        float g = 0.f;
        for (int ks = 0; ks < 16; ++ks) g += pg[(size_t)ks*16384 + r*128 + d];
        float val = (g - (float)NSAMP*ms[r]*ms[d]) * (1.0f/(NSAMP-1));
        float uval = (d > r) ? val : ((d == r) ? 0.5f*val : 0.0f);
        Uh[((size_t)w*128 + r)*128 + d] = (_Float16)uval;
    }
}

// ---- qconv3: fused rnorm + normalize + fp16 + B-fragment-major repack ---------
// grid 256 (one block per b), block 512 (8 waves).
// Output layout (halves): qf[b][tile(64)][kk(4)][lane(64)][e(8)]
//   where lane holds q[c = kk*32 + (lane>>4)*8 + e][i = tile*16 + (lane&15)]
__global__ __launch_bounds__(512) void qconv3_kernel(const float* __restrict__ x1,
                                                     _Float16* __restrict__ qf) {
    __shared__ _Float16 T[128*258];
    __shared__ float rnL[128];
    int tid = threadIdx.x, lane = tid & 63, wv = tid >> 6;
    int b = blockIdx.x;
    const float* xb = x1 + (size_t)b * C_CH * HW;

    // phase A: rn per channel (full-row square sums)
    #pragma unroll
    for (int cc = 0; cc < 16; ++cc) {
        int c = wv*16 + cc;
        const f32x4* row = (const f32x4*)(xb + (size_t)c * HW);
        float s = 0.f;
        #pragma unroll
        for (int j = 0; j < 4; ++j) {
            f32x4 v = row[lane + j*64];
            s += v[0]*v[0] + v[1]*v[1] + v[2]*v[2] + v[3]*v[3];
        }
        #pragma unroll
        for (int off = 32; off; off >>= 1) s += __shfl_xor(s, off, 64);
        if (lane == 0) rnL[c] = 1.0f / sqrtf(s);
    }
    __syncthreads();

    // phase B: per 256-px chunk: stage normalized fp16 transpose, emit fragments
    for (int ic = 0; ic < 4; ++ic) {
        #pragma unroll
        for (int cc = 0; cc < 16; ++cc) {
            int c = wv*16 + cc;
            f32x4 v = *(const f32x4*)(xb + (size_t)c * HW + ic*256 + lane*4);
            float sc = rnL[c];
            half4 h = {(_Float16)(v[0]*sc), (_Float16)(v[1]*sc),
                       (_Float16)(v[2]*sc), (_Float16)(v[3]*sc)};
            *(half4*)(&T[c*258 + lane*4]) = h;
        }
        __syncthreads();
        #pragma unroll
        for (int it = 0; it < 8; ++it) {
            int slot = it*512 + tid;          // 0..4095 = tile_loc(16) x kk(4) x lane(64)
            int tl = slot >> 8;
            int kk = (slot >> 6) & 3;
            int ln = slot & 63;
            int i_loc = tl*16 + (ln & 15);
            int c0 = kk*32 + (ln >> 4)*8;
            half8 pk;
            #pragma unroll
            for (int e = 0; e < 8; ++e) pk[e] = T[(c0+e)*258 + i_loc];
            size_t tile_g = (size_t)ic*16 + tl;
            *(half8*)(qf + (((size_t)b*64 + tile_g)*4 + kk)*512 + ln*8) = pk;
        }
        __syncthreads();
    }
}

// ---- sim v6: zero-LDS, zero-barrier; A in regs once; frag-major q from global -
// grid 1024: b = bid&255, wg = bid>>8 (same-b blocks -> same XCD for L2 reuse)
// block 256 = 4 waves; wave = one w = wg*4+wv; loops 64 i-tiles of 16 px
__global__ __launch_bounds__(256, 2) void sim_kernel(const _Float16* __restrict__ qf,
                                                     const _Float16* __restrict__ Uh,
                                                     float* __restrict__ out) {
    int tid = threadIdx.x, lane = tid & 63, wv = tid >> 6;
    int lr = lane & 15, lg = lane >> 4;
    int b = blockIdx.x & 255, wg = blockIdx.x >> 8;
    int w = wg*4 + wv;

    // A: 20 upper-triangular fragments (m <= 2kk+1), loaded once
    half8 A[20];
    {
        const _Float16* Ub = Uh + (size_t)w*C_CH*C_CH + (size_t)lr*C_CH + lg*8;
        int idx = 0;
        #pragma unroll
        for (int kk = 0; kk < 4; ++kk)
            #pragma unroll
            for (int m = 0; m <= 2*kk+1; ++m) {
                A[idx] = *(const half8*)(Ub + (size_t)m*16*C_CH + kk*32);
                ++idx;
            }
    }

    const _Float16* qfb = qf + (size_t)b * 131072;   // 64 tiles * 4 kk * 512 halves
    int offB  = lane*8;                               // B-frag lane offset (halves)
    int offDq = (lg>>1)*128 + lr*8 + (lg&1)*4;        // dq lane offset (halves)
    float* ob = out + ((size_t)b*W_CLS + w)*HW;

#define LOADT(Bx, Dx, t) do {                                               \
        const _Float16* tb = qfb + (size_t)(t)*2048;                        \
        _Pragma("unroll")                                                   \
        for (int kk = 0; kk < 4; ++kk)                                      \
            Bx[kk] = *(const half8*)(tb + kk*512 + offB);                   \
        _Pragma("unroll")                                                   \
        for (int m = 0; m < 8; ++m)                                         \
            Dx[m] = *(const half4*)(tb + m*256 + offDq);                    \
    } while (0)

#define COMPUTE(Bx, Dx, t) do {                                             \
        f32x4 acc[8];                                                       \
        _Pragma("unroll")                                                   \
        for (int m = 0; m < 8; ++m) acc[m] = (f32x4){0.f,0.f,0.f,0.f};      \
        __builtin_amdgcn_s_setprio(1);                                      \
        {                                                                   \
            int idx = 0;                                                    \
            _Pragma("unroll")                                               \
            for (int kk = 0; kk < 4; ++kk)                                  \
                _Pragma("unroll")                                           \
                for (int m = 0; m <= 2*kk+1; ++m) {                         \
                    acc[m] = __builtin_amdgcn_mfma_f32_16x16x32_f16(        \
                                 A[idx], Bx[kk], acc[m], 0, 0, 0);          \
                    ++idx;                                                  \
                }                                                           \
        }                                                                   \
        __builtin_amdgcn_s_setprio(0);                                      \
        float s = 0.f;                                                      \
        _Pragma("unroll")                                                   \
        for (int m = 0; m < 8; ++m) {                                       \
            s = fmaf((float)Dx[m][0], acc[m][0], s);                        \
            s = fmaf((float)Dx[m][1], acc[m][1], s);                        \
            s = fmaf((float)Dx[m][2], acc[m][2], s);                        \
            s = fmaf((float)Dx[m][3], acc[m][3], s);                        \
        }                                                                   \
        s += __shfl_xor(s, 16, 64);                                         \
        s += __shfl_xor(s, 32, 64);                                         \
        if (lane < 16) ob[(t)*16 + lr] = 2.0f * s;                          \
    } while (0)

    half8 B0[4], B1[4];
    half4 D0[8], D1[8];
    LOADT(B0, D0, 0);
    for (int t = 0; t < 64; t += 2) {
        int t1 = (t+1 < 64) ? t+1 : 63;
        int t2 = (t+2 < 64) ? t+2 : 63;
        LOADT(B1, D1, t1);
        COMPUTE(B0, D0, t);
        LOADT(B0, D0, t2);
        COMPUTE(B1, D1, t1);
    }
#undef LOADT
#undef COMPUTE
}

// ================= fallback path (small ws) =================

__global__ __launch_bounds__(256) void rnorm_kernel(const float* __restrict__ x1,
                                                    float* __restrict__ rn) {
    int row  = blockIdx.x * 4 + (threadIdx.x >> 6);
    int lane = threadIdx.x & 63;
    const float4* p = (const float4*)(x1 + (size_t)row * HW);
    float s = 0.f;
    #pragma unroll
    for (int it = 0; it < 4; ++it) {
        float4 v = p[lane + it * 64];
        s += v.x*v.x + v.y*v.y + v.z*v.z + v.w*v.w;
    }
    for (int off = 32; off; off >>= 1) s += __shfl_down(s, off, 64);
    if (lane == 0) rn[row] = 1.0f / sqrtf(s);
}

__global__ __launch_bounds__(256) void mean_kernel_f(const float* __restrict__ x2,
                                                     float* __restrict__ mean) {
    int wc = blockIdx.x;
    int w  = wc >> 7, c = wc & 127;
    const float* base = x2 + ((size_t)(w * SHOT) * C_CH + c) * HW;
    int tid = threadIdx.x;
    float sum = 0.f;
    for (int s = 0; s < SHOT; ++s) {
        const float* row = base + (size_t)s * C_CH * HW;
        for (int p = tid; p < HW; p += 256) sum += row[p];
    }
    for (int off = 32; off; off >>= 1) sum += __shfl_down(sum, off, 64);
    __shared__ float red[4];
    int lane = tid & 63, wv = tid >> 6;
    if (lane == 0) red[wv] = sum;
    __syncthreads();
    if (tid == 0) mean[wc] = (red[0] + red[1] + red[2] + red[3]) * (1.0f / NSAMP);
}

__global__ __launch_bounds__(256) void cova_kernel_f(const float* __restrict__ x2,
                                                     const float* __restrict__ mean,
                                                     _Float16* __restrict__ covah) {
    int bid = blockIdx.x;
    int w  = bid >> 4;
    int c0 = ((bid >> 2) & 3) * 32;
    int d0 = (bid & 3) * 32;
    __shared__ float As[32][33];
    __shared__ float Bs[32][33];
    int tid = threadIdx.x;
    int ty = tid >> 4, tx = tid & 15;
    int lrr = tid >> 3, lc = (tid & 7) * 4;
    const float* base = x2 + (size_t)w * SHOT * C_CH * HW;
    float acc00 = 0.f, acc01 = 0.f, acc10 = 0.f, acc11 = 0.f;
    for (int k0 = 0; k0 < NSAMP; k0 += 32) {
        int s = k0 >> 10, p = k0 & 1023;
        const float4 a4 = *(const float4*)(base + ((size_t)s * C_CH + (c0 + lrr)) * HW + p + lc);
        const float4 b4 = *(const float4*)(base + ((size_t)s * C_CH + (d0 + lrr)) * HW + p + lc);
        As[lrr][lc+0] = a4.x; As[lrr][lc+1] = a4.y; As[lrr][lc+2] = a4.z; As[lrr][lc+3] = a4.w;
        Bs[lrr][lc+0] = b4.x; Bs[lrr][lc+1] = b4.y; Bs[lrr][lc+2] = b4.z; Bs[lrr][lc+3] = b4.w;
        __syncthreads();
        #pragma unroll
        for (int kk = 0; kk < 32; ++kk) {
            float a0 = As[ty*2][kk],   a1 = As[ty*2+1][kk];
            float b0 = Bs[tx*2][kk],   b1 = Bs[tx*2+1][kk];
            acc00 = fmaf(a0, b0, acc00);
            acc01 = fmaf(a0, b1, acc01);
            acc10 = fmaf(a1, b0, acc10);
            acc11 = fmaf(a1, b1, acc11);
        }
        __syncthreads();
    }
    const float inv = 1.0f / (NSAMP - 1);
    int c = c0 + ty * 2, d = d0 + tx * 2;
    float mc0 = mean[w*128 + c],     mc1 = mean[w*128 + c + 1];
    float md0 = mean[w*128 + d],     md1 = mean[w*128 + d + 1];
    _Float16* o = covah + ((size_t)w * 128 + c) * 128 + d;
    o[0]   = (_Float16)((acc00 - (float)NSAMP * mc0 * md0) * inv);
    o[1]   = (_Float16)((acc01 - (float)NSAMP * mc0 * md1) * inv);
    o[128] = (_Float16)((acc10 - (float)NSAMP * mc1 * md0) * inv);
    o[129] = (_Float16)((acc11 - (float)NSAMP * mc1 * md1) * inv);
}

#define LDQ 136
__global__ __launch_bounds__(512) void sim_kernel_f(const float* __restrict__ x1,
                                                    const _Float16* __restrict__ Ch,
                                                    const float* __restrict__ rn,
                                                    float* __restrict__ out) {
    __shared__ _Float16 qT[128][LDQ];
    __shared__ float simbuf[2][128];
    int tid = threadIdx.x;
    int bq  = blockIdx.x;
    int b   = bq >> 3;
    int i0  = (bq & 7) * 128;
    {
        int c  = tid >> 2;
        int iq = (tid & 3) * 32;
        const float* src = x1 + ((size_t)b * C_CH + c) * HW + i0 + iq;
        float scale = rn[b * C_CH + c];
        #pragma unroll
        for (int j4 = 0; j4 < 8; ++j4) {
            f32x4 v = *(const f32x4*)(src + j4 * 4);
            qT[iq + j4*4 + 0][c] = (_Float16)(v[0] * scale);
            qT[iq + j4*4 + 1][c] = (_Float16)(v[1] * scale);
            qT[iq + j4*4 + 2][c] = (_Float16)(v[2] * scale);
            qT[iq + j4*4 + 3][c] = (_Float16)(v[3] * scale);
        }
    }
    __syncthreads();
    int lane = tid & 63;
    int wv   = tid >> 6;
    int mh   = wv >> 2;
    int nq   = wv & 3;
    int d0w  = mh * 64;
    int iw   = nq * 32;
    int lr   = lane & 15;
    int lg   = lane >> 4;
    float qd[4][2][4];
    #pragma unroll
    for (int m = 0; m < 4; ++m)
        #pragma unroll
        for (int n = 0; n < 2; ++n) {
            half4 hq = *(const half4*)&qT[iw + n*16 + lr][d0w + m*16 + lg*4];
            qd[m][n][0] = (float)hq[0];
            qd[m][n][1] = (float)hq[1];
            qd[m][n][2] = (float)hq[2];
            qd[m][n][3] = (float)hq[3];
        }
    for (int w = 0; w < W_CLS; ++w) {
        const _Float16* Cw = Ch + (size_t)w * C_CH * C_CH;
        half8 A[4][4];
        #pragma unroll
        for (int m = 0; m < 4; ++m)
            #pragma unroll
            for (int k = 0; k < 4; ++k)
                A[m][k] = *(const half8*)(Cw + (size_t)(d0w + m*16 + lr) * C_CH + k*32 + lg*8);
        f32x4 acc[4][2];
        #pragma unroll
        for (int m = 0; m < 4; ++m)
            #pragma unroll
            for (int n = 0; n < 2; ++n)
                acc[m][n] = (f32x4){0.f, 0.f, 0.f, 0.f};
        #pragma unroll
        for (int k = 0; k < 4; ++k) {
            #pragma unroll
            for (int n = 0; n < 2; ++n) {
                half8 Bf = *(const half8*)&qT[iw + n*16 + lr][k*32 + lg*8];
                #pragma unroll
                for (int m = 0; m < 4; ++m)
                    acc[m][n] = __builtin_amdgcn_mfma_f32_16x16x32_f16(A[m][k], Bf, acc[m][n], 0, 0, 0);
            }
        }
        float s0 = 0.f, s1 = 0.f;
        #pragma unroll
        for (int m = 0; m < 4; ++m) {
            #pragma unroll
            for (int r = 0; r < 4; ++r) {
                s0 = fmaf(qd[m][0][r], acc[m][0][r], s0);
                s1 = fmaf(qd[m][1][r], acc[m][1][r], s1);
            }
        }
        s0 += __shfl_xor(s0, 16); s0 += __shfl_xor(s0, 32);
        s1 += __shfl_xor(s1, 16); s1 += __shfl_xor(s1, 32);
        if (lane < 16) {
            simbuf[mh][iw + 0*16 + lane] = s0;
            simbuf[mh][iw + 1*16 + lane] = s1;
        }
        __syncthreads();
        if (tid < 128)
            out[((size_t)b * W_CLS + w) * HW + i0 + tid] = simbuf[0][tid] + simbuf[1][tid];
        __syncthreads();
    }
}

// ================= host =================

extern "C" void kernel_launch(void* const* d_in, const int* in_sizes, int n_in,
                              void* d_out, int out_size, void* d_ws, size_t ws_size,
                              hipStream_t stream) {
    (void)in_sizes; (void)n_in; (void)out_size;
    const float* x1 = (const float*)d_in[0];   // [256,128,32,32]
    const float* x2 = (const float*)d_in[1];   // [16,8,128,32,32]
    float* out = (float*)d_out;

    char* ws = (char*)d_ws;
    const size_t OFF_QF  = 0;                          // 256*131072 fp16 = 64 MB
    const size_t OFF_PG  = 67108864;                   // 16.78 MB
    const size_t OFF_PM  = OFF_PG  + 16777216;         // 128 KB
    const size_t OFF_UH  = OFF_PM  + 131072;           // 512 KB
    const size_t OFF_RN  = OFF_UH  + 524288;           // 128 KB (fallback only)
    const size_t NEED    = OFF_RN  + 131072;

    if (ws_size >= NEED) {
        _Float16* qf  = (_Float16*)(ws + OFF_QF);
        float*    PG  = (float*)(ws + OFF_PG);
        float*    pm  = (float*)(ws + OFF_PM);
        _Float16* Uh  = (_Float16*)(ws + OFF_UH);
        cova_part    <<<256,  512, 0, stream>>>(x2, PG, pm);
        cova_reduce  <<<128,  256, 0, stream>>>(PG, pm, Uh);
        qconv3_kernel<<<256,  512, 0, stream>>>(x1, qf);
        sim_kernel   <<<1024, 256, 0, stream>>>(qf, Uh, out);
    } else {
        float*    mean = (float*)ws;
        float*    rn   = mean + W_CLS*C_CH;
        _Float16* Ch   = (_Float16*)(rn + B_Q*C_CH);
        mean_kernel_f<<<W_CLS*C_CH,  256, 0, stream>>>(x2, mean);
        cova_kernel_f<<<W_CLS*16,    256, 0, stream>>>(x2, mean, Ch);
        rnorm_kernel <<<B_Q*C_CH/4,  256, 0, stream>>>(x1, rn);
        sim_kernel_f <<<B_Q*8,       512, 0, stream>>>(x1, Ch, rn, out);
    }
}